// Round 3
// baseline (111.134 us; speedup 1.0000x reference)
//
#include <hip/hip_runtime.h>
#include <math.h>

// SinusoidalPositionEmbeddings: out[i,j] = sin(t[i]*div(j)) if j even else cos(t[i]*div(j))
// div(j) = exp(-ln(10000) * (j - j%2) / (C-1)),  C = 1024, B = 131072.
// Pure 536.9 MB fp32 write stream. v3: 16 rows/block (64KB), t staged in LDS,
// non-temporal float4 stores, x4-unrolled store loop -> store queue never drains.

#define EMBED_C 1024
#define C4 (EMBED_C / 4)      // 256 float4 per row
#define ROWS_PER_BLK 16

typedef float f4 __attribute__((ext_vector_type(4)));  // POD vector for nt store

__global__ void __launch_bounds__(256)
sinembed_kernel(const float* __restrict__ t, float* __restrict__ out, int nrows) {
    __shared__ float ts[ROWS_PER_BLK];

    const int tid = threadIdx.x;               // 0..255 == col4 index
    const int r0  = blockIdx.x * ROWS_PER_BLK;

    // Stage this block's t-values: one coalesced 64B load by lanes 0..15.
    if (tid < ROWS_PER_BLK) {
        const int r = r0 + tid;
        ts[tid] = (r < nrows) ? t[r] : 0.0f;
    }

    // coef = -log2(10000) / (C-1); div_term = 2^(coef * two_i)
    constexpr float coef = (float)(-13.287712379549449 / 1023.0);
    const int   j0   = tid * 4;                            // even channel base
    const float div0 = exp2f(coef * (float)j0);            // channels j0, j0+1
    const float div1 = exp2f(coef * (float)(j0 + 2));      // channels j0+2, j0+3

    __syncthreads();

    f4* o = reinterpret_cast<f4*>(out) + (size_t)r0 * C4 + tid;

    if (r0 + ROWS_PER_BLK <= nrows) {
        #pragma unroll 4
        for (int row = 0; row < ROWS_PER_BLK; ++row) {
            const float tv = ts[row];          // broadcast LDS read, conflict-free
            float s0, c0, s1, c1;
            __sincosf(tv * div0, &s0, &c0);
            __sincosf(tv * div1, &s1, &c1);
            f4 v = {s0, c0, s1, c1};
            __builtin_nontemporal_store(v, &o[(size_t)row * C4]);  // 1024B/wave, L2-bypass
        }
    } else {
        // Tail guard (not hit for B=131072: 131072 % 16 == 0).
        for (int row = 0; row < ROWS_PER_BLK && (r0 + row) < nrows; ++row) {
            const float tv = ts[row];
            float s0, c0, s1, c1;
            __sincosf(tv * div0, &s0, &c0);
            __sincosf(tv * div1, &s1, &c1);
            f4 v = {s0, c0, s1, c1};
            __builtin_nontemporal_store(v, &o[(size_t)row * C4]);
        }
    }
}

extern "C" void kernel_launch(void* const* d_in, const int* in_sizes, int n_in,
                              void* d_out, int out_size, void* d_ws, size_t ws_size,
                              hipStream_t stream) {
    const float* t   = (const float*)d_in[0];
    float*       out = (float*)d_out;

    const int nrows = out_size / EMBED_C;                        // 131072
    const int grid  = (nrows + ROWS_PER_BLK - 1) / ROWS_PER_BLK; // 8192 blocks

    sinembed_kernel<<<grid, 256, 0, stream>>>(t, out, nrows);
}